// Round 7
// baseline (1251.731 us; speedup 1.0000x reference)
//
#include <hip/hip_runtime.h>
#include <hip/hip_cooperative_groups.h>
#include <hip/hip_bf16.h>
#include <math.h>

namespace cg = cooperative_groups;

#define NROWS 100000
#define DIM 128
#define NGRAPH 16
#define EPSV 1e-12f

// ---- fallback (round-4) geometry ----
#define NCHUNK 128
#define CHROWS 782
#define SZ_SUMP (NGRAPH*NCHUNK*DIM)
#define SZ_WV   (NGRAPH*2*DIM)
#define SZ_OP   (NGRAPH*NCHUNK*2*DIM)
#define OFF_SUMP 0
#define OFF_WV1 (OFF_SUMP + SZ_SUMP)
#define OFF_C1  (OFF_WV1 + SZ_WV)
#define OFF_O1P (OFF_C1 + 32)
#define OFF_WV2 (OFF_O1P + SZ_OP)
#define OFF_C2  (OFF_WV2 + SZ_WV)
#define OFF_O2P (OFF_C2 + 32)
#define OFF_S   (OFF_O2P + SZ_OP)

// ---- mega-kernel geometry ----
#define MCH 64        // chunks per graph -> 16*64 = 1024 blocks, one per (g,c)
#define MCHR 1563     // ceil(100000/64)
#define MEGA_F0 2000000          // float offset of mega region in ws (disjoint from fallback)
#define SCALE26 67108864.0
#define INV26 (1.0/67108864.0)
#define INV26N (1.0/(67108864.0*100000.0))

__device__ __forceinline__ const float* graph_ptr(const float* x1, const float* x2, int g) {
    return (g < 8) ? (x1 + (size_t)g * NROWS * DIM) : (x2 + (size_t)(g - 8) * NROWS * DIM);
}

__device__ __forceinline__ float4 ld4(const float* p) {
    return *reinterpret_cast<const float4*>(p);
}

// 16-lane all-reduce sum entirely on the VALU pipe via DPP (no DS ops).
__device__ __forceinline__ float red16(float x) {
    int t;
    t = __builtin_amdgcn_update_dpp(0, __float_as_int(x), 0xB1, 0xF, 0xF, true);
    x += __int_as_float(t);
    t = __builtin_amdgcn_update_dpp(0, __float_as_int(x), 0x4E, 0xF, 0xF, true);
    x += __int_as_float(t);
    t = __builtin_amdgcn_update_dpp(0, __float_as_int(x), 0x141, 0xF, 0xF, true);
    x += __int_as_float(t);
    t = __builtin_amdgcn_update_dpp(0, __float_as_int(x), 0x140, 0xF, 0xF, true);
    x += __int_as_float(t);
    return x;
}

__device__ __forceinline__ float dot8(float4 v0, float4 v1, float4 w0, float4 w1) {
    float d = v0.x * w0.x;
    d = fmaf(v0.y, w0.y, d); d = fmaf(v0.z, w0.z, d); d = fmaf(v0.w, w0.w, d);
    d = fmaf(v1.x, w1.x, d); d = fmaf(v1.y, w1.y, d); d = fmaf(v1.z, w1.z, d);
    d = fmaf(v1.w, w1.w, d);
    return d;
}

__device__ __forceinline__ void acc4(float4& a, float f, float4 v) {
    a.x = fmaf(f, v.x, a.x); a.y = fmaf(f, v.y, a.y);
    a.z = fmaf(f, v.z, a.z); a.w = fmaf(f, v.w, a.w);
}

__device__ __forceinline__ void body2(float4 v0, float4 v1,
                                      float4 w0a, float4 w0b, float4 w1a, float4 w1b,
                                      float cc0, float cc1,
                                      float ap0, float an0, float ap1, float an1,
                                      float4& a0l, float4& a0h, float4& a1l, float4& a1h) {
    float d0 = red16(dot8(v0, v1, w0a, w0b));
    float d1 = red16(dot8(v0, v1, w1a, w1b));
    float at0 = (d0 + cc0 >= 0.f) ? ap0 : an0;
    float at1 = (d1 + cc1 >= 0.f) ? ap1 : an1;
    acc4(a0l, at0, v0); acc4(a0h, at0, v1);
    acc4(a1l, at1, v0); acc4(a1h, at1, v1);
}

__device__ __forceinline__ void body3(float4 v0, float4 v1,
                                      float4 wA0a, float4 wA0b, float4 wA1a, float4 wA1b,
                                      float4 wB0a, float4 wB0b, float4 wB1a, float4 wB1b,
                                      float cA0, float cA1, float cB0, float cB1,
                                      float ap0, float an0, float ap1, float an1,
                                      float4& a0l, float4& a0h, float4& a1l, float4& a1h) {
    float dA0 = red16(dot8(v0, v1, wA0a, wA0b));
    float dA1 = red16(dot8(v0, v1, wA1a, wA1b));
    float dB0 = red16(dot8(v0, v1, wB0a, wB0b));
    float dB1 = red16(dot8(v0, v1, wB1a, wB1b));
    float at10 = (dA0 + cA0 >= 0.f) ? ap0 : an0;
    float at11 = (dA1 + cA1 >= 0.f) ? ap1 : an1;
    float at20 = (fmaf(at10, dB0, cB0) >= 0.f) ? ap0 : an0;
    float at21 = (fmaf(at11, dB1, cB1) >= 0.f) ? ap1 : an1;
    float f0 = at10 * at20, f1 = at11 * at21;
    acc4(a0l, f0, v0); acc4(a0h, f0, v1);
    acc4(a1l, f1, v0); acc4(a1h, f1, v1);
}

__device__ __forceinline__ void atomic_acc26(long long* p, float v) {
    long long q = (long long)rint((double)v * SCALE26);
    atomicAdd((unsigned long long*)p, (unsigned long long)q);
}

// ======================= MEGA (cooperative, single launch) =======================

struct KParams {
    const float *x1, *x2, *W, *V, *Wt, *U, *bA, *Vn, *Wn, *bn, *p0, *p1, *p2, *p3;
    float *out, *ws;
};

// prep phase body: mean -> h = tanh(mean@W) -> wvec = Va + Wt@h, c = Vb.h + b
// called by one block per (g,i); barriers are block-local.
__device__ void prep_dev(const KParams& P, float* smem, int g, int i, int tid,
                         const long long* src, float* wv, float* cc) {
    float* mean = smem;
    float* h    = smem + 128;
    float* red2 = smem + 256;
    int t = tid & 127;
    if (tid < 128) mean[t] = (float)((double)src[t] * INV26N);
    __syncthreads();
    float hv = 0.f;
    if (tid < 128) {
        const float* W = P.W + (size_t)i * DIM * DIM;
        for (int d = 0; d < DIM; ++d) hv = fmaf(mean[d], W[d * DIM + t], hv);
        h[t] = tanhf(hv);
    }
    __syncthreads();
    if (tid < 128) {
        const float* Wt = P.Wt + (size_t)i * DIM * DIM;
        const float* Va = P.V + (size_t)i * 2 * DIM;
        float w = Va[t];
        for (int e = 0; e < DIM; ++e) w = fmaf(Wt[t * DIM + e], h[e], w);
        wv[((size_t)g * 2 + i) * DIM + t] = w;
        red2[t] = Va[DIM + t] * h[t];
    }
    __syncthreads();
    for (int k = 64; k; k >>= 1) {
        if (tid < k) red2[tid] += red2[tid + k];
        __syncthreads();
    }
    if (tid == 0) cc[g * 2 + i] = red2[0] + P.bA[i];
}

__global__ __launch_bounds__(256, 4) void k_mega(KParams P) {
    cg::grid_group grid = cg::this_grid();
    __shared__ __align__(16) float smem[4096];   // 16 KiB, reused across phases
    const int bid = blockIdx.x, tid = threadIdx.x;

    float* wv1  = P.ws + MEGA_F0;
    float* c1   = wv1 + 4096;
    float* wv2  = c1 + 32;
    float* c2   = wv2 + 4096;
    float* sout = c2 + 32;
    long long* acc     = (long long*)(P.ws + MEGA_F0 + 8448);  // 8B-aligned
    long long* sum_acc = acc;                 // [16][128]
    long long* o1_acc  = acc + 2048;          // [16][2][128]
    long long* g_acc   = acc + 2048 + 4096;   // [16][2][128]

    // phase Z: zero accumulators (idempotent per call)
    { int idx = bid * 256 + tid; if (idx < 10240) acc[idx] = 0; }
    grid.sync();

    const int g = bid >> 6, c = bid & (MCH - 1);
    const float* xg = graph_ptr(P.x1, P.x2, g);
    const int r0 = c * MCHR, r1 = min(r0 + MCHR, NROWS);

    // phase 1: column sums -> sum_acc (int64 fixed-point, deterministic)
    {
        int lane = tid & 31, grp = tid >> 5, col = lane * 4;
        float ax = 0.f, ay = 0.f, az = 0.f, aw = 0.f;
        int r = r0 + grp;
        for (; r + 8 < r1; r += 16) {
            float4 a = ld4(xg + (size_t)r * DIM + col);
            float4 b = ld4(xg + (size_t)(r + 8) * DIM + col);
            ax += a.x; ay += a.y; az += a.z; aw += a.w;
            ax += b.x; ay += b.y; az += b.z; aw += b.w;
        }
        if (r < r1) {
            float4 a = ld4(xg + (size_t)r * DIM + col);
            ax += a.x; ay += a.y; az += a.z; aw += a.w;
        }
        float4* l4 = (float4*)smem;
        l4[tid] = make_float4(ax, ay, az, aw);
        __syncthreads();
        if (tid < 32) {
            float4 t = l4[tid];
            for (int k = 1; k < 8; ++k) {
                float4 o = l4[k * 32 + tid];
                t.x += o.x; t.y += o.y; t.z += o.z; t.w += o.w;
            }
            int d = tid * 4;
            atomic_acc26(&sum_acc[g * DIM + d + 0], t.x);
            atomic_acc26(&sum_acc[g * DIM + d + 1], t.y);
            atomic_acc26(&sum_acc[g * DIM + d + 2], t.z);
            atomic_acc26(&sum_acc[g * DIM + d + 3], t.w);
        }
    }
    grid.sync();

    // phase 2: prep iter1 (32 blocks)
    if (bid < 32) prep_dev(P, smem, bid >> 1, bid & 1, tid, &sum_acc[(bid >> 1) * DIM], wv1, c1);
    grid.sync();

    // phase 3: pass2 -> o1_acc
    {
        int l16 = tid & 15, slot = tid >> 4, cb = l16 * 4;
        float4 w0a = ld4(wv1 + ((size_t)g * 2 + 0) * DIM + cb);
        float4 w0b = ld4(wv1 + ((size_t)g * 2 + 0) * DIM + 64 + cb);
        float4 w1a = ld4(wv1 + ((size_t)g * 2 + 1) * DIM + cb);
        float4 w1b = ld4(wv1 + ((size_t)g * 2 + 1) * DIM + 64 + cb);
        float cc0 = c1[g * 2 + 0], cc1 = c1[g * 2 + 1];
        float u0 = P.U[0], u1 = P.U[1];
        float sp = 1.f / (1.f + expf(-1.f)), sn = 1.f / (1.f + expf(1.f));
        float ap0 = u0 * sp, an0 = u0 * sn, ap1 = u1 * sp, an1 = u1 * sn;
        float4 a0l = make_float4(0, 0, 0, 0), a0h = make_float4(0, 0, 0, 0);
        float4 a1l = make_float4(0, 0, 0, 0), a1h = make_float4(0, 0, 0, 0);
        int r = r0 + slot;
        for (; r + 16 < r1; r += 32) {
            const float* p = xg + (size_t)r * DIM + cb;
            const float* q = xg + (size_t)(r + 16) * DIM + cb;
            float4 v0 = ld4(p), v1 = ld4(p + 64);
            float4 y0 = ld4(q), y1 = ld4(q + 64);
            body2(v0, v1, w0a, w0b, w1a, w1b, cc0, cc1, ap0, an0, ap1, an1, a0l, a0h, a1l, a1h);
            body2(y0, y1, w0a, w0b, w1a, w1b, cc0, cc1, ap0, an0, ap1, an1, a0l, a0h, a1l, a1h);
        }
        for (; r < r1; r += 16) {
            const float* p = xg + (size_t)r * DIM + cb;
            float4 v0 = ld4(p), v1 = ld4(p + 64);
            body2(v0, v1, w0a, w0b, w1a, w1b, cc0, cc1, ap0, an0, ap1, an1, a0l, a0h, a1l, a1h);
        }
        __syncthreads();   // smem handoff from previous phase usage
        float* red = smem; // [2][16][128]
        *(float4*)&red[(0 * 16 + slot) * DIM + cb] = a0l;
        *(float4*)&red[(0 * 16 + slot) * DIM + 64 + cb] = a0h;
        *(float4*)&red[(1 * 16 + slot) * DIM + cb] = a1l;
        *(float4*)&red[(1 * 16 + slot) * DIM + 64 + cb] = a1h;
        __syncthreads();
        int i = tid >> 7, d = tid & 127;
        float s = 0.f;
        #pragma unroll
        for (int k = 0; k < 16; ++k) s += red[(i * 16 + k) * DIM + d];
        atomic_acc26(&o1_acc[((size_t)g * 2 + i) * DIM + d], s);
    }
    grid.sync();

    // phase 4: prep iter2 (32 blocks) — mean2 = out1/N per (g,i)
    if (bid < 32) prep_dev(P, smem, bid >> 1, bid & 1, tid,
                           &o1_acc[((size_t)(bid >> 1) * 2 + (bid & 1)) * DIM], wv2, c2);
    grid.sync();

    // phase 5: pass3 -> g_acc
    {
        int l16 = tid & 15, slot = tid >> 4, cb = l16 * 4;
        float4 wA0a = ld4(wv1 + ((size_t)g * 2 + 0) * DIM + cb);
        float4 wA0b = ld4(wv1 + ((size_t)g * 2 + 0) * DIM + 64 + cb);
        float4 wA1a = ld4(wv1 + ((size_t)g * 2 + 1) * DIM + cb);
        float4 wA1b = ld4(wv1 + ((size_t)g * 2 + 1) * DIM + 64 + cb);
        float4 wB0a = ld4(wv2 + ((size_t)g * 2 + 0) * DIM + cb);
        float4 wB0b = ld4(wv2 + ((size_t)g * 2 + 0) * DIM + 64 + cb);
        float4 wB1a = ld4(wv2 + ((size_t)g * 2 + 1) * DIM + cb);
        float4 wB1b = ld4(wv2 + ((size_t)g * 2 + 1) * DIM + 64 + cb);
        float cA0 = c1[g * 2 + 0], cA1 = c1[g * 2 + 1];
        float cB0 = c2[g * 2 + 0], cB1 = c2[g * 2 + 1];
        float u0 = P.U[0], u1 = P.U[1];
        float sp = 1.f / (1.f + expf(-1.f)), sn = 1.f / (1.f + expf(1.f));
        float ap0 = u0 * sp, an0 = u0 * sn, ap1 = u1 * sp, an1 = u1 * sn;
        float4 a0l = make_float4(0, 0, 0, 0), a0h = make_float4(0, 0, 0, 0);
        float4 a1l = make_float4(0, 0, 0, 0), a1h = make_float4(0, 0, 0, 0);
        int r = r0 + slot;
        for (; r + 16 < r1; r += 32) {
            const float* p = xg + (size_t)r * DIM + cb;
            const float* q = xg + (size_t)(r + 16) * DIM + cb;
            float4 v0 = ld4(p), v1 = ld4(p + 64);
            float4 y0 = ld4(q), y1 = ld4(q + 64);
            body3(v0, v1, wA0a, wA0b, wA1a, wA1b, wB0a, wB0b, wB1a, wB1b,
                  cA0, cA1, cB0, cB1, ap0, an0, ap1, an1, a0l, a0h, a1l, a1h);
            body3(y0, y1, wA0a, wA0b, wA1a, wA1b, wB0a, wB0b, wB1a, wB1b,
                  cA0, cA1, cB0, cB1, ap0, an0, ap1, an1, a0l, a0h, a1l, a1h);
        }
        for (; r < r1; r += 16) {
            const float* p = xg + (size_t)r * DIM + cb;
            float4 v0 = ld4(p), v1 = ld4(p + 64);
            body3(v0, v1, wA0a, wA0b, wA1a, wA1b, wB0a, wB0b, wB1a, wB1b,
                  cA0, cA1, cB0, cB1, ap0, an0, ap1, an1, a0l, a0h, a1l, a1h);
        }
        __syncthreads();
        float* red = smem;
        *(float4*)&red[(0 * 16 + slot) * DIM + cb] = a0l;
        *(float4*)&red[(0 * 16 + slot) * DIM + 64 + cb] = a0h;
        *(float4*)&red[(1 * 16 + slot) * DIM + cb] = a1l;
        *(float4*)&red[(1 * 16 + slot) * DIM + 64 + cb] = a1h;
        __syncthreads();
        int i = tid >> 7, d = tid & 127;
        float s = 0.f;
        #pragma unroll
        for (int k = 0; k < 16; ++k) s += red[(i * 16 + k) * DIM + d];
        atomic_acc26(&g_acc[((size_t)g * 2 + i) * DIM + d], s);
    }
    grid.sync();

    // phase 6: NTN (128 blocks: one per (pair b, feature f))
    if (bid < 128) {
        int b = bid >> 4, f = bid & 15, e = tid;
        float* g1s = smem; float* g2s = smem + 256; float* red = smem + 512;
        int i = e >> 7, d = e & 127;
        g1s[e] = (float)((double)g_acc[((size_t)b * 2 + i) * DIM + d] * INV26);
        g2s[e] = (float)((double)g_acc[((size_t)(8 + b) * 2 + i) * DIM + d] * INV26);
        __syncthreads();
        const float* Wf = P.Wn + (size_t)f * 256 * 256;
        float a = 0.f;
        for (int dd = 0; dd < 256; ++dd) a = fmaf(Wf[(size_t)dd * 256 + e], g1s[dd], a);
        float p = a * g2s[e];
        p = fmaf(P.Vn[(size_t)f * 512 + e], g1s[e], p);
        p = fmaf(P.Vn[(size_t)f * 512 + 256 + e], g2s[e], p);
        red[e] = p;
        __syncthreads();
        for (int k = 128; k; k >>= 1) {
            if (e < k) red[e] += red[e + k];
            __syncthreads();
        }
        if (e == 0) sout[b * 16 + f] = red[0] + P.bn[f];
    }
    grid.sync();

    // phase 7: l1-norm + relu + projection chain
    if (bid < 8 && tid == 0) {
        int b = bid;
        float s[16]; float l1 = 0.f;
        for (int f = 0; f < 16; ++f) { s[f] = sout[b * 16 + f]; l1 += fabsf(s[f]); }
        float inv = 1.f / fmaxf(l1, EPSV);
        float y[16];
        for (int f = 0; f < 16; ++f) { float t = s[f] * inv; y[f] = t > 0.f ? t : 0.f; }
        float v2[4], v1[8], Pr[16];
        for (int j = 0; j < 4; ++j) v2[j] = P.p3[0] * P.p2[j] + P.p3[1] * P.p2[4 + j];
        for (int j = 0; j < 8; ++j) { float a = 0.f; for (int k = 0; k < 4; ++k) a = fmaf(v2[k], P.p1[k * 8 + j], a); v1[j] = a; }
        for (int j = 0; j < 16; ++j) { float a = 0.f; for (int k = 0; k < 8; ++k) a = fmaf(v1[k], P.p0[k * 16 + j], a); Pr[j] = a; }
        float o = 0.f;
        for (int f = 0; f < 16; ++f) o = fmaf(Pr[f], y[f], o);
        P.out[b] = o;
    }
}

// ======================= FALLBACK (round-4 sequence, proven 476-486us) =======================

__global__ __launch_bounds__(256) void k_sum(const float* __restrict__ x1,
                                             const float* __restrict__ x2,
                                             float* __restrict__ sump) {
    int g = blockIdx.x >> 7, c = blockIdx.x & (NCHUNK - 1);
    const float* xg = graph_ptr(x1, x2, g);
    int lane = threadIdx.x & 31, grp = threadIdx.x >> 5;
    int col = lane * 4;
    float ax = 0.f, ay = 0.f, az = 0.f, aw = 0.f;
    int r0 = c * CHROWS, r1 = min(r0 + CHROWS, NROWS);
    int r = r0 + grp;
    for (; r + 8 < r1; r += 16) {
        float4 a = ld4(xg + (size_t)r * DIM + col);
        float4 b = ld4(xg + (size_t)(r + 8) * DIM + col);
        ax += a.x; ay += a.y; az += a.z; aw += a.w;
        ax += b.x; ay += b.y; az += b.z; aw += b.w;
    }
    if (r < r1) {
        float4 a = ld4(xg + (size_t)r * DIM + col);
        ax += a.x; ay += a.y; az += a.z; aw += a.w;
    }
    __shared__ float4 lds[256];
    lds[threadIdx.x] = make_float4(ax, ay, az, aw);
    __syncthreads();
    if (threadIdx.x < 32) {
        float4 t = lds[threadIdx.x];
        for (int k = 1; k < 8; ++k) {
            float4 o = lds[k * 32 + threadIdx.x];
            t.x += o.x; t.y += o.y; t.z += o.z; t.w += o.w;
        }
        *reinterpret_cast<float4*>(sump + ((size_t)g * NCHUNK + c) * DIM + threadIdx.x * 4) = t;
    }
}

__global__ __launch_bounds__(256) void k_prep(const float* __restrict__ src, int phase,
                                              const float* __restrict__ W_att,
                                              const float* __restrict__ V_att,
                                              const float* __restrict__ Wt_att,
                                              const float* __restrict__ b_att,
                                              float* __restrict__ wv, float* __restrict__ cc) {
    int g = blockIdx.x >> 1, i = blockIdx.x & 1;
    int tid = threadIdx.x, t = tid & 127, half = tid >> 7;
    __shared__ float mean[DIM], h[DIM], red2[256];
    float s = 0.f;
    if (phase == 1) {
        for (int c = half; c < NCHUNK; c += 2) s += src[((size_t)g * NCHUNK + c) * DIM + t];
    } else {
        for (int c = half; c < NCHUNK; c += 2) s += src[(((size_t)g * NCHUNK + c) * 2 + i) * DIM + t];
    }
    red2[tid] = s; __syncthreads();
    if (half == 0) mean[t] = (red2[t] + red2[t + 128]) * (1.f / (float)NROWS);
    __syncthreads();
    const float* W = W_att + (size_t)i * DIM * DIM;
    float hv = 0.f;
    for (int d = half * 64; d < half * 64 + 64; ++d) hv = fmaf(mean[d], W[d * DIM + t], hv);
    red2[tid] = hv; __syncthreads();
    if (half == 0) h[t] = tanhf(red2[t] + red2[t + 128]);
    __syncthreads();
    const float* Wt = Wt_att + (size_t)i * DIM * DIM;
    float w = 0.f;
    for (int e = half * 64; e < half * 64 + 64; ++e) w = fmaf(Wt[t * DIM + e], h[e], w);
    red2[tid] = w; __syncthreads();
    const float* Va = V_att + (size_t)i * 2 * DIM;
    if (half == 0) wv[((size_t)g * 2 + i) * DIM + t] = Va[t] + red2[t] + red2[t + 128];
    __syncthreads();
    if (half == 0) red2[t] = Va[DIM + t] * h[t];
    __syncthreads();
    for (int k = 64; k; k >>= 1) {
        if (tid < k) red2[tid] += red2[tid + k];
        __syncthreads();
    }
    if (tid == 0) cc[g * 2 + i] = red2[0] + b_att[i];
}

__global__ __launch_bounds__(256) void k_pass2(const float* __restrict__ x1,
                                               const float* __restrict__ x2,
                                               const float* __restrict__ wv1,
                                               const float* __restrict__ c1,
                                               const float* __restrict__ U_att,
                                               float* __restrict__ o1p) {
    int g = blockIdx.x >> 7, c = blockIdx.x & (NCHUNK - 1);
    const float* xg = graph_ptr(x1, x2, g);
    int tid = threadIdx.x;
    int l16 = tid & 15, slot = tid >> 4, cb = l16 * 4;
    float4 w0a = ld4(wv1 + ((size_t)g * 2 + 0) * DIM + cb);
    float4 w0b = ld4(wv1 + ((size_t)g * 2 + 0) * DIM + 64 + cb);
    float4 w1a = ld4(wv1 + ((size_t)g * 2 + 1) * DIM + cb);
    float4 w1b = ld4(wv1 + ((size_t)g * 2 + 1) * DIM + 64 + cb);
    float cc0 = c1[g * 2 + 0], cc1 = c1[g * 2 + 1];
    float u0 = U_att[0], u1 = U_att[1];
    float sp = 1.f / (1.f + expf(-1.f)), sn = 1.f / (1.f + expf(1.f));
    float ap0 = u0 * sp, an0 = u0 * sn, ap1 = u1 * sp, an1 = u1 * sn;
    float4 a0l = make_float4(0, 0, 0, 0), a0h = make_float4(0, 0, 0, 0);
    float4 a1l = make_float4(0, 0, 0, 0), a1h = make_float4(0, 0, 0, 0);
    int r0 = c * CHROWS, r1 = min(r0 + CHROWS, NROWS);
    int r = r0 + slot;
    for (; r + 16 < r1; r += 32) {
        const float* p = xg + (size_t)r * DIM + cb;
        const float* q = xg + (size_t)(r + 16) * DIM + cb;
        float4 v0 = ld4(p), v1 = ld4(p + 64);
        float4 y0 = ld4(q), y1 = ld4(q + 64);
        body2(v0, v1, w0a, w0b, w1a, w1b, cc0, cc1, ap0, an0, ap1, an1, a0l, a0h, a1l, a1h);
        body2(y0, y1, w0a, w0b, w1a, w1b, cc0, cc1, ap0, an0, ap1, an1, a0l, a0h, a1l, a1h);
    }
    for (; r < r1; r += 16) {
        const float* p = xg + (size_t)r * DIM + cb;
        float4 v0 = ld4(p), v1 = ld4(p + 64);
        body2(v0, v1, w0a, w0b, w1a, w1b, cc0, cc1, ap0, an0, ap1, an1, a0l, a0h, a1l, a1h);
    }
    __shared__ float red[2][16][DIM];
    *reinterpret_cast<float4*>(&red[0][slot][cb]) = a0l;
    *reinterpret_cast<float4*>(&red[0][slot][64 + cb]) = a0h;
    *reinterpret_cast<float4*>(&red[1][slot][cb]) = a1l;
    *reinterpret_cast<float4*>(&red[1][slot][64 + cb]) = a1h;
    __syncthreads();
    int i = tid >> 7, d = tid & 127;
    float s = 0.f;
    #pragma unroll
    for (int k = 0; k < 16; ++k) s += red[i][k][d];
    o1p[(((size_t)g * NCHUNK + c) * 2 + i) * DIM + d] = s;
}

__global__ __launch_bounds__(256) void k_pass3(const float* __restrict__ x1,
                                               const float* __restrict__ x2,
                                               const float* __restrict__ wv1,
                                               const float* __restrict__ c1,
                                               const float* __restrict__ wv2,
                                               const float* __restrict__ c2,
                                               const float* __restrict__ U_att,
                                               float* __restrict__ o2p) {
    int g = blockIdx.x >> 7, c = blockIdx.x & (NCHUNK - 1);
    const float* xg = graph_ptr(x1, x2, g);
    int tid = threadIdx.x;
    int l16 = tid & 15, slot = tid >> 4, cb = l16 * 4;
    float4 wA0a = ld4(wv1 + ((size_t)g * 2 + 0) * DIM + cb);
    float4 wA0b = ld4(wv1 + ((size_t)g * 2 + 0) * DIM + 64 + cb);
    float4 wA1a = ld4(wv1 + ((size_t)g * 2 + 1) * DIM + cb);
    float4 wA1b = ld4(wv1 + ((size_t)g * 2 + 1) * DIM + 64 + cb);
    float4 wB0a = ld4(wv2 + ((size_t)g * 2 + 0) * DIM + cb);
    float4 wB0b = ld4(wv2 + ((size_t)g * 2 + 0) * DIM + 64 + cb);
    float4 wB1a = ld4(wv2 + ((size_t)g * 2 + 1) * DIM + cb);
    float4 wB1b = ld4(wv2 + ((size_t)g * 2 + 1) * DIM + 64 + cb);
    float cA0 = c1[g * 2 + 0], cA1 = c1[g * 2 + 1];
    float cB0 = c2[g * 2 + 0], cB1 = c2[g * 2 + 1];
    float u0 = U_att[0], u1 = U_att[1];
    float sp = 1.f / (1.f + expf(-1.f)), sn = 1.f / (1.f + expf(1.f));
    float ap0 = u0 * sp, an0 = u0 * sn, ap1 = u1 * sp, an1 = u1 * sn;
    float4 a0l = make_float4(0, 0, 0, 0), a0h = make_float4(0, 0, 0, 0);
    float4 a1l = make_float4(0, 0, 0, 0), a1h = make_float4(0, 0, 0, 0);
    int r0 = c * CHROWS, r1 = min(r0 + CHROWS, NROWS);
    int r = r0 + slot;
    for (; r + 16 < r1; r += 32) {
        const float* p = xg + (size_t)r * DIM + cb;
        const float* q = xg + (size_t)(r + 16) * DIM + cb;
        float4 v0 = ld4(p), v1 = ld4(p + 64);
        float4 y0 = ld4(q), y1 = ld4(q + 64);
        body3(v0, v1, wA0a, wA0b, wA1a, wA1b, wB0a, wB0b, wB1a, wB1b,
              cA0, cA1, cB0, cB1, ap0, an0, ap1, an1, a0l, a0h, a1l, a1h);
        body3(y0, y1, wA0a, wA0b, wA1a, wA1b, wB0a, wB0b, wB1a, wB1b,
              cA0, cA1, cB0, cB1, ap0, an0, ap1, an1, a0l, a0h, a1l, a1h);
    }
    for (; r < r1; r += 16) {
        const float* p = xg + (size_t)r * DIM + cb;
        float4 v0 = ld4(p), v1 = ld4(p + 64);
        body3(v0, v1, wA0a, wA0b, wA1a, wA1b, wB0a, wB0b, wB1a, wB1b,
              cA0, cA1, cB0, cB1, ap0, an0, ap1, an1, a0l, a0h, a1l, a1h);
    }
    __shared__ float red[2][16][DIM];
    *reinterpret_cast<float4*>(&red[0][slot][cb]) = a0l;
    *reinterpret_cast<float4*>(&red[0][slot][64 + cb]) = a0h;
    *reinterpret_cast<float4*>(&red[1][slot][cb]) = a1l;
    *reinterpret_cast<float4*>(&red[1][slot][64 + cb]) = a1h;
    __syncthreads();
    int i = tid >> 7, d = tid & 127;
    float s = 0.f;
    #pragma unroll
    for (int k = 0; k < 16; ++k) s += red[i][k][d];
    o2p[(((size_t)g * NCHUNK + c) * 2 + i) * DIM + d] = s;
}

__global__ __launch_bounds__(256) void k_ntn(const float* __restrict__ o2p,
                                             const float* __restrict__ V_ntn,
                                             const float* __restrict__ W_ntn,
                                             const float* __restrict__ b_ntn,
                                             float* __restrict__ sout) {
    int b = blockIdx.x >> 4, f = blockIdx.x & 15;
    int e = threadIdx.x;
    __shared__ float g1s[256], g2s[256], red[256];
    int i = e >> 7, d = e & 127;
    float s1 = 0.f, s2 = 0.f;
    for (int c = 0; c < NCHUNK; ++c) {
        s1 += o2p[(((size_t)b * NCHUNK + c) * 2 + i) * DIM + d];
        s2 += o2p[(((size_t)(8 + b) * NCHUNK + c) * 2 + i) * DIM + d];
    }
    g1s[e] = s1; g2s[e] = s2;
    __syncthreads();
    const float* Wf = W_ntn + (size_t)f * 256 * 256;
    float acc = 0.f;
    for (int dd = 0; dd < 256; ++dd) acc = fmaf(Wf[(size_t)dd * 256 + e], g1s[dd], acc);
    float p = acc * g2s[e];
    p = fmaf(V_ntn[(size_t)f * 512 + e], g1s[e], p);
    p = fmaf(V_ntn[(size_t)f * 512 + 256 + e], g2s[e], p);
    red[e] = p;
    __syncthreads();
    for (int k = 128; k; k >>= 1) {
        if (e < k) red[e] += red[e + k];
        __syncthreads();
    }
    if (e == 0) sout[b * 16 + f] = red[0] + b_ntn[f];
}

__global__ __launch_bounds__(64) void k_out(const float* __restrict__ sout,
                                            const float* __restrict__ p0,
                                            const float* __restrict__ p1,
                                            const float* __restrict__ p2,
                                            const float* __restrict__ p3,
                                            float* __restrict__ out) {
    int b = blockIdx.x;
    if (threadIdx.x != 0) return;
    float s[16]; float l1 = 0.f;
    for (int f = 0; f < 16; ++f) { s[f] = sout[b * 16 + f]; l1 += fabsf(s[f]); }
    float inv = 1.f / fmaxf(l1, EPSV);
    float y[16];
    for (int f = 0; f < 16; ++f) { float t = s[f] * inv; y[f] = t > 0.f ? t : 0.f; }
    float v2[4], v1[8], P[16];
    for (int j = 0; j < 4; ++j) v2[j] = p3[0] * p2[j] + p3[1] * p2[4 + j];
    for (int j = 0; j < 8; ++j) { float a = 0.f; for (int k = 0; k < 4; ++k) a = fmaf(v2[k], p1[k * 8 + j], a); v1[j] = a; }
    for (int j = 0; j < 16; ++j) { float a = 0.f; for (int k = 0; k < 8; ++k) a = fmaf(v1[k], p0[k * 16 + j], a); P[j] = a; }
    float o = 0.f;
    for (int f = 0; f < 16; ++f) o = fmaf(P[f], y[f], o);
    out[b] = o;
}

extern "C" void kernel_launch(void* const* d_in, const int* in_sizes, int n_in,
                              void* d_out, int out_size, void* d_ws, size_t ws_size,
                              hipStream_t stream) {
    const float* x1    = (const float*)d_in[0];
    const float* x2    = (const float*)d_in[1];
    const float* W_att = (const float*)d_in[2];
    const float* V_att = (const float*)d_in[3];
    const float* Wt_att= (const float*)d_in[4];
    const float* U_att = (const float*)d_in[5];
    const float* b_att = (const float*)d_in[6];
    const float* V_ntn = (const float*)d_in[7];
    const float* W_ntn = (const float*)d_in[8];
    const float* b_ntn = (const float*)d_in[9];
    const float* p0    = (const float*)d_in[10];
    const float* p1    = (const float*)d_in[11];
    const float* p2    = (const float*)d_in[12];
    const float* p3    = (const float*)d_in[13];
    float* ws  = (float*)d_ws;
    float* out = (float*)d_out;

    KParams P{x1, x2, W_att, V_att, Wt_att, U_att, b_att,
              V_ntn, W_ntn, b_ntn, p0, p1, p2, p3, out, ws};
    void* args[] = {&P};
    hipError_t err = hipLaunchCooperativeKernel((const void*)k_mega, dim3(16 * MCH),
                                                dim3(256), args, 0, stream);
    if (err != hipSuccess) {
        (void)hipGetLastError();  // clear error state; run proven multi-kernel path
        k_sum<<<NGRAPH * NCHUNK, 256, 0, stream>>>(x1, x2, ws + OFF_SUMP);
        k_prep<<<NGRAPH * 2, 256, 0, stream>>>(ws + OFF_SUMP, 1, W_att, V_att, Wt_att, b_att,
                                               ws + OFF_WV1, ws + OFF_C1);
        k_pass2<<<NGRAPH * NCHUNK, 256, 0, stream>>>(x1, x2, ws + OFF_WV1, ws + OFF_C1, U_att,
                                                     ws + OFF_O1P);
        k_prep<<<NGRAPH * 2, 256, 0, stream>>>(ws + OFF_O1P, 2, W_att, V_att, Wt_att, b_att,
                                               ws + OFF_WV2, ws + OFF_C2);
        k_pass3<<<NGRAPH * NCHUNK, 256, 0, stream>>>(x1, x2, ws + OFF_WV1, ws + OFF_C1,
                                                     ws + OFF_WV2, ws + OFF_C2, U_att,
                                                     ws + OFF_O2P);
        k_ntn<<<8 * 16, 256, 0, stream>>>(ws + OFF_O2P, V_ntn, W_ntn, b_ntn, ws + OFF_S);
        k_out<<<8, 64, 0, stream>>>(ws + OFF_S, p0, p1, p2, p3, out);
    }
}

// Round 8
// 476.126 us; speedup vs baseline: 2.6290x; 2.6290x over previous
//
#include <hip/hip_runtime.h>
#include <hip/hip_bf16.h>
#include <math.h>

#define NROWS 100000
#define DIM 128
#define NGRAPH 16
#define NCHUNK 128
#define CHROWS 782   // ceil(100000/128)
#define EPSV 1e-12f

// workspace layout (float offsets)
#define SZ_SUMP (NGRAPH*NCHUNK*DIM)          // 262144
#define SZ_WV   (NGRAPH*2*DIM)               // 4096
#define SZ_OP   (NGRAPH*NCHUNK*2*DIM)        // 524288
#define OFF_SUMP 0
#define OFF_WV1 (OFF_SUMP + SZ_SUMP)
#define OFF_C1  (OFF_WV1 + SZ_WV)
#define OFF_O1P (OFF_C1 + 32)
#define OFF_WV2 (OFF_O1P + SZ_OP)
#define OFF_C2  (OFF_WV2 + SZ_WV)
#define OFF_O2P (OFF_C2 + 32)
#define OFF_G   (OFF_O2P + SZ_OP)            // [16][256]
#define OFF_S   (OFF_G + NGRAPH*256)         // [8][16]

__device__ __forceinline__ const float* graph_ptr(const float* x1, const float* x2, int g) {
    return (g < 8) ? (x1 + (size_t)g * NROWS * DIM) : (x2 + (size_t)(g - 8) * NROWS * DIM);
}

// 16-lane all-reduce sum entirely on the VALU pipe via DPP (no DS ops).
// Steps: xor1 (quad_perm[1,0,3,2]=0xB1), xor2 (quad_perm[2,3,0,1]=0x4E),
// row_half_mirror (0x141, pairs quads), row_mirror (0x140, pairs 8-groups).
// All involutions; every lane of the 16-group ends with the identical sum.
__device__ __forceinline__ float red16(float x) {
    int t;
    t = __builtin_amdgcn_update_dpp(0, __float_as_int(x), 0xB1, 0xF, 0xF, true);
    x += __int_as_float(t);
    t = __builtin_amdgcn_update_dpp(0, __float_as_int(x), 0x4E, 0xF, 0xF, true);
    x += __int_as_float(t);
    t = __builtin_amdgcn_update_dpp(0, __float_as_int(x), 0x141, 0xF, 0xF, true);
    x += __int_as_float(t);
    t = __builtin_amdgcn_update_dpp(0, __float_as_int(x), 0x140, 0xF, 0xF, true);
    x += __int_as_float(t);
    return x;
}

__device__ __forceinline__ float dot8(float4 v0, float4 v1, float4 w0, float4 w1) {
    float d = v0.x * w0.x;
    d = fmaf(v0.y, w0.y, d); d = fmaf(v0.z, w0.z, d); d = fmaf(v0.w, w0.w, d);
    d = fmaf(v1.x, w1.x, d); d = fmaf(v1.y, w1.y, d); d = fmaf(v1.z, w1.z, d);
    d = fmaf(v1.w, w1.w, d);
    return d;
}

__device__ __forceinline__ float4 ld4(const float* p) {
    return *reinterpret_cast<const float4*>(p);
}

// Pass 1: per-chunk column sums of each graph -> sump[g][c][128]
__global__ __launch_bounds__(256) void k_sum(const float* __restrict__ x1,
                                             const float* __restrict__ x2,
                                             float* __restrict__ sump) {
    int g = blockIdx.x >> 7, c = blockIdx.x & (NCHUNK - 1);
    const float* xg = graph_ptr(x1, x2, g);
    int lane = threadIdx.x & 31, grp = threadIdx.x >> 5;
    int col = lane * 4;
    float ax = 0.f, ay = 0.f, az = 0.f, aw = 0.f;
    int r0 = c * CHROWS, r1 = min(r0 + CHROWS, NROWS);
    for (int r = r0 + grp; r < r1; r += 8) {
        float4 v = ld4(xg + (size_t)r * DIM + col);
        ax += v.x; ay += v.y; az += v.z; aw += v.w;
    }
    __shared__ float4 lds[256];
    lds[threadIdx.x] = make_float4(ax, ay, az, aw);
    __syncthreads();
    if (threadIdx.x < 32) {
        float4 t = lds[threadIdx.x];
        for (int k = 1; k < 8; ++k) {
            float4 o = lds[k * 32 + threadIdx.x];
            t.x += o.x; t.y += o.y; t.z += o.z; t.w += o.w;
        }
        *reinterpret_cast<float4*>(sump + ((size_t)g * NCHUNK + c) * DIM + threadIdx.x * 4) = t;
    }
}

// Glue: mean -> h = tanh(mean@W) -> wvec = Va + Wt@h, c = Vb.h + b
__global__ __launch_bounds__(128) void k_prep(const float* __restrict__ src, int phase,
                                              const float* __restrict__ W_att,
                                              const float* __restrict__ V_att,
                                              const float* __restrict__ Wt_att,
                                              const float* __restrict__ b_att,
                                              float* __restrict__ wv, float* __restrict__ cc) {
    int g = blockIdx.x >> 1, i = blockIdx.x & 1;
    int t = threadIdx.x;
    __shared__ float mean[DIM], h[DIM], red[DIM];
    float s = 0.f;
    if (phase == 1) {
        for (int c = 0; c < NCHUNK; ++c) s += src[((size_t)g * NCHUNK + c) * DIM + t];
    } else {
        for (int c = 0; c < NCHUNK; ++c) s += src[(((size_t)g * NCHUNK + c) * 2 + i) * DIM + t];
    }
    mean[t] = s / (float)NROWS;
    __syncthreads();
    const float* W = W_att + (size_t)i * DIM * DIM;
    float hv = 0.f;
    for (int d = 0; d < DIM; ++d) hv = fmaf(mean[d], W[d * DIM + t], hv);
    h[t] = tanhf(hv);
    __syncthreads();
    const float* Va = V_att + (size_t)i * 2 * DIM;
    const float* Vb = Va + DIM;
    const float* Wt = Wt_att + (size_t)i * DIM * DIM;
    float w = Va[t];
    for (int e = 0; e < DIM; ++e) w = fmaf(Wt[t * DIM + e], h[e], w);
    wv[((size_t)g * 2 + i) * DIM + t] = w;
    red[t] = Vb[t] * h[t];
    __syncthreads();
    for (int k = 64; k; k >>= 1) { if (t < k) red[t] += red[t + k]; __syncthreads(); }
    if (t == 0) cc[g * 2 + i] = red[0] + b_att[i];
}

// Pass 2: att1 per row (sign-select), accumulate out1 = sum att1*x (per-chunk partials)
// Layout: 16 lanes per row (8 floats each), 16 row-slots per 256-thread block.
__global__ __launch_bounds__(256) void k_pass2(const float* __restrict__ x1,
                                               const float* __restrict__ x2,
                                               const float* __restrict__ wv1,
                                               const float* __restrict__ c1,
                                               const float* __restrict__ U_att,
                                               float* __restrict__ o1p) {
    int g = blockIdx.x >> 7, c = blockIdx.x & (NCHUNK - 1);
    const float* xg = graph_ptr(x1, x2, g);
    int tid = threadIdx.x;
    int l16 = tid & 15, slot = tid >> 4;
    int colb = l16 * 8;
    float4 w0a = ld4(wv1 + ((size_t)g * 2 + 0) * DIM + colb);
    float4 w0b = ld4(wv1 + ((size_t)g * 2 + 0) * DIM + colb + 4);
    float4 w1a = ld4(wv1 + ((size_t)g * 2 + 1) * DIM + colb);
    float4 w1b = ld4(wv1 + ((size_t)g * 2 + 1) * DIM + colb + 4);
    float cc0 = c1[g * 2 + 0], cc1 = c1[g * 2 + 1];
    // att = u*sigmoid(clamp(s*1e12,-1,1)) == u*sigmoid(sign(s)) (|s|<1e-12 has prob ~0)
    float u0 = U_att[0], u1 = U_att[1];
    float sp = 1.f / (1.f + expf(-1.f)), sn = 1.f / (1.f + expf(1.f));
    float ap0 = u0 * sp, an0 = u0 * sn, ap1 = u1 * sp, an1 = u1 * sn;
    float4 a0l = make_float4(0, 0, 0, 0), a0h = make_float4(0, 0, 0, 0);
    float4 a1l = make_float4(0, 0, 0, 0), a1h = make_float4(0, 0, 0, 0);
    int r0 = c * CHROWS, r1 = min(r0 + CHROWS, NROWS);
    for (int r = r0 + slot; r < r1; r += 16) {
        const float* p = xg + (size_t)r * DIM + colb;
        float4 v0 = ld4(p), v1 = ld4(p + 4);
        float d0 = red16(dot8(v0, v1, w0a, w0b));
        float d1 = red16(dot8(v0, v1, w1a, w1b));
        float at0 = (d0 + cc0 >= 0.f) ? ap0 : an0;
        float at1 = (d1 + cc1 >= 0.f) ? ap1 : an1;
        a0l.x = fmaf(at0, v0.x, a0l.x); a0l.y = fmaf(at0, v0.y, a0l.y);
        a0l.z = fmaf(at0, v0.z, a0l.z); a0l.w = fmaf(at0, v0.w, a0l.w);
        a0h.x = fmaf(at0, v1.x, a0h.x); a0h.y = fmaf(at0, v1.y, a0h.y);
        a0h.z = fmaf(at0, v1.z, a0h.z); a0h.w = fmaf(at0, v1.w, a0h.w);
        a1l.x = fmaf(at1, v0.x, a1l.x); a1l.y = fmaf(at1, v0.y, a1l.y);
        a1l.z = fmaf(at1, v0.z, a1l.z); a1l.w = fmaf(at1, v0.w, a1l.w);
        a1h.x = fmaf(at1, v1.x, a1h.x); a1h.y = fmaf(at1, v1.y, a1h.y);
        a1h.z = fmaf(at1, v1.z, a1h.z); a1h.w = fmaf(at1, v1.w, a1h.w);
    }
    __shared__ float red[2][16][DIM];   // 16 KiB
    *reinterpret_cast<float4*>(&red[0][slot][colb]) = a0l;
    *reinterpret_cast<float4*>(&red[0][slot][colb + 4]) = a0h;
    *reinterpret_cast<float4*>(&red[1][slot][colb]) = a1l;
    *reinterpret_cast<float4*>(&red[1][slot][colb + 4]) = a1h;
    __syncthreads();
    int i = tid >> 7, d = tid & 127;
    float s = 0.f;
    #pragma unroll
    for (int k = 0; k < 16; ++k) s += red[i][k][d];
    o1p[(((size_t)g * NCHUNK + c) * 2 + i) * DIM + d] = s;
}

// Pass 3: recompute att1, att2 via sign-select, accumulate att1*att2*x
__global__ __launch_bounds__(256) void k_pass3(const float* __restrict__ x1,
                                               const float* __restrict__ x2,
                                               const float* __restrict__ wv1,
                                               const float* __restrict__ c1,
                                               const float* __restrict__ wv2,
                                               const float* __restrict__ c2,
                                               const float* __restrict__ U_att,
                                               float* __restrict__ o2p) {
    int g = blockIdx.x >> 7, c = blockIdx.x & (NCHUNK - 1);
    const float* xg = graph_ptr(x1, x2, g);
    int tid = threadIdx.x;
    int l16 = tid & 15, slot = tid >> 4;
    int colb = l16 * 8;
    float4 wA0a = ld4(wv1 + ((size_t)g * 2 + 0) * DIM + colb);
    float4 wA0b = ld4(wv1 + ((size_t)g * 2 + 0) * DIM + colb + 4);
    float4 wA1a = ld4(wv1 + ((size_t)g * 2 + 1) * DIM + colb);
    float4 wA1b = ld4(wv1 + ((size_t)g * 2 + 1) * DIM + colb + 4);
    float4 wB0a = ld4(wv2 + ((size_t)g * 2 + 0) * DIM + colb);
    float4 wB0b = ld4(wv2 + ((size_t)g * 2 + 0) * DIM + colb + 4);
    float4 wB1a = ld4(wv2 + ((size_t)g * 2 + 1) * DIM + colb);
    float4 wB1b = ld4(wv2 + ((size_t)g * 2 + 1) * DIM + colb + 4);
    float cA0 = c1[g * 2 + 0], cA1 = c1[g * 2 + 1];
    float cB0 = c2[g * 2 + 0], cB1 = c2[g * 2 + 1];
    float u0 = U_att[0], u1 = U_att[1];
    float sp = 1.f / (1.f + expf(-1.f)), sn = 1.f / (1.f + expf(1.f));
    float ap0 = u0 * sp, an0 = u0 * sn, ap1 = u1 * sp, an1 = u1 * sn;
    float4 a0l = make_float4(0, 0, 0, 0), a0h = make_float4(0, 0, 0, 0);
    float4 a1l = make_float4(0, 0, 0, 0), a1h = make_float4(0, 0, 0, 0);
    int r0 = c * CHROWS, r1 = min(r0 + CHROWS, NROWS);
    for (int r = r0 + slot; r < r1; r += 16) {
        const float* p = xg + (size_t)r * DIM + colb;
        float4 v0 = ld4(p), v1 = ld4(p + 4);
        float dA0 = red16(dot8(v0, v1, wA0a, wA0b));
        float dA1 = red16(dot8(v0, v1, wA1a, wA1b));
        float dB0 = red16(dot8(v0, v1, wB0a, wB0b));
        float dB1 = red16(dot8(v0, v1, wB1a, wB1b));
        float at10 = (dA0 + cA0 >= 0.f) ? ap0 : an0;
        float at11 = (dA1 + cA1 >= 0.f) ? ap1 : an1;
        float at20 = (fmaf(at10, dB0, cB0) >= 0.f) ? ap0 : an0;
        float at21 = (fmaf(at11, dB1, cB1) >= 0.f) ? ap1 : an1;
        float f0 = at10 * at20, f1 = at11 * at21;
        a0l.x = fmaf(f0, v0.x, a0l.x); a0l.y = fmaf(f0, v0.y, a0l.y);
        a0l.z = fmaf(f0, v0.z, a0l.z); a0l.w = fmaf(f0, v0.w, a0l.w);
        a0h.x = fmaf(f0, v1.x, a0h.x); a0h.y = fmaf(f0, v1.y, a0h.y);
        a0h.z = fmaf(f0, v1.z, a0h.z); a0h.w = fmaf(f0, v1.w, a0h.w);
        a1l.x = fmaf(f1, v0.x, a1l.x); a1l.y = fmaf(f1, v0.y, a1l.y);
        a1l.z = fmaf(f1, v0.z, a1l.z); a1l.w = fmaf(f1, v0.w, a1l.w);
        a1h.x = fmaf(f1, v1.x, a1h.x); a1h.y = fmaf(f1, v1.y, a1h.y);
        a1h.z = fmaf(f1, v1.z, a1h.z); a1h.w = fmaf(f1, v1.w, a1h.w);
    }
    __shared__ float red[2][16][DIM];   // 16 KiB
    *reinterpret_cast<float4*>(&red[0][slot][colb]) = a0l;
    *reinterpret_cast<float4*>(&red[0][slot][colb + 4]) = a0h;
    *reinterpret_cast<float4*>(&red[1][slot][colb]) = a1l;
    *reinterpret_cast<float4*>(&red[1][slot][colb + 4]) = a1h;
    __syncthreads();
    int i = tid >> 7, d = tid & 127;
    float s = 0.f;
    #pragma unroll
    for (int k = 0; k < 16; ++k) s += red[i][k][d];
    o2p[(((size_t)g * NCHUNK + c) * 2 + i) * DIM + d] = s;
}

// Reduce per-chunk out2 partials -> g vectors [16][256] (concat i=0, i=1)
__global__ __launch_bounds__(256) void k_reduceG(const float* __restrict__ o2p,
                                                 float* __restrict__ gv) {
    int g = blockIdx.x, t = threadIdx.x;
    int i = t >> 7, d = t & 127;
    float s = 0.f;
    for (int c = 0; c < NCHUNK; ++c) s += o2p[(((size_t)g * NCHUNK + c) * 2 + i) * DIM + d];
    gv[(size_t)g * 256 + t] = s;
}

// NTN raw scores: one block per (pair b, feature f)
__global__ __launch_bounds__(256) void k_ntn(const float* __restrict__ gv,
                                             const float* __restrict__ V_ntn,
                                             const float* __restrict__ W_ntn,
                                             const float* __restrict__ b_ntn,
                                             float* __restrict__ sout) {
    int b = blockIdx.x >> 4, f = blockIdx.x & 15;
    int e = threadIdx.x;
    __shared__ float g1s[256], g2s[256], red[256];
    g1s[e] = gv[(size_t)b * 256 + e];
    g2s[e] = gv[(size_t)(8 + b) * 256 + e];
    __syncthreads();
    const float* Wf = W_ntn + (size_t)f * 256 * 256;
    float acc = 0.f;
    for (int d = 0; d < 256; ++d) acc = fmaf(Wf[(size_t)d * 256 + e], g1s[d], acc);
    float p = acc * g2s[e];
    p = fmaf(V_ntn[(size_t)f * 512 + e], g1s[e], p);
    p = fmaf(V_ntn[(size_t)f * 512 + 256 + e], g2s[e], p);
    red[e] = p;
    __syncthreads();
    for (int k = 128; k; k >>= 1) { if (e < k) red[e] += red[e + k]; __syncthreads(); }
    if (e == 0) sout[b * 16 + f] = red[0] + b_ntn[f];
}

// Final: l1-normalize, relu, projection chain -> out[b]
__global__ __launch_bounds__(64) void k_out(const float* __restrict__ sout,
                                            const float* __restrict__ p0,
                                            const float* __restrict__ p1,
                                            const float* __restrict__ p2,
                                            const float* __restrict__ p3,
                                            float* __restrict__ out) {
    int b = blockIdx.x;
    if (threadIdx.x != 0) return;
    float s[16]; float l1 = 0.f;
    for (int f = 0; f < 16; ++f) { s[f] = sout[b * 16 + f]; l1 += fabsf(s[f]); }
    float inv = 1.f / fmaxf(l1, EPSV);
    float y[16];
    for (int f = 0; f < 16; ++f) { float t = s[f] * inv; y[f] = t > 0.f ? t : 0.f; }
    float v2[4], v1[8], P[16];
    for (int j = 0; j < 4; ++j) v2[j] = p3[0] * p2[j] + p3[1] * p2[4 + j];
    for (int j = 0; j < 8; ++j) { float a = 0.f; for (int k = 0; k < 4; ++k) a = fmaf(v2[k], p1[k * 8 + j], a); v1[j] = a; }
    for (int j = 0; j < 16; ++j) { float a = 0.f; for (int k = 0; k < 8; ++k) a = fmaf(v1[k], p0[k * 16 + j], a); P[j] = a; }
    float o = 0.f;
    for (int f = 0; f < 16; ++f) o = fmaf(P[f], y[f], o);
    out[b] = o;
}

extern "C" void kernel_launch(void* const* d_in, const int* in_sizes, int n_in,
                              void* d_out, int out_size, void* d_ws, size_t ws_size,
                              hipStream_t stream) {
    const float* x1    = (const float*)d_in[0];
    const float* x2    = (const float*)d_in[1];
    const float* W_att = (const float*)d_in[2];
    const float* V_att = (const float*)d_in[3];
    const float* Wt_att= (const float*)d_in[4];
    const float* U_att = (const float*)d_in[5];
    const float* b_att = (const float*)d_in[6];
    const float* V_ntn = (const float*)d_in[7];
    const float* W_ntn = (const float*)d_in[8];
    const float* b_ntn = (const float*)d_in[9];
    const float* p0    = (const float*)d_in[10];
    const float* p1    = (const float*)d_in[11];
    const float* p2    = (const float*)d_in[12];
    const float* p3    = (const float*)d_in[13];
    float* ws  = (float*)d_ws;
    float* out = (float*)d_out;

    k_sum<<<NGRAPH * NCHUNK, 256, 0, stream>>>(x1, x2, ws + OFF_SUMP);
    k_prep<<<NGRAPH * 2, 128, 0, stream>>>(ws + OFF_SUMP, 1, W_att, V_att, Wt_att, b_att,
                                           ws + OFF_WV1, ws + OFF_C1);
    k_pass2<<<NGRAPH * NCHUNK, 256, 0, stream>>>(x1, x2, ws + OFF_WV1, ws + OFF_C1, U_att,
                                                 ws + OFF_O1P);
    k_prep<<<NGRAPH * 2, 128, 0, stream>>>(ws + OFF_O1P, 2, W_att, V_att, Wt_att, b_att,
                                           ws + OFF_WV2, ws + OFF_C2);
    k_pass3<<<NGRAPH * NCHUNK, 256, 0, stream>>>(x1, x2, ws + OFF_WV1, ws + OFF_C1,
                                                 ws + OFF_WV2, ws + OFF_C2, U_att,
                                                 ws + OFF_O2P);
    k_reduceG<<<NGRAPH, 256, 0, stream>>>(ws + OFF_O2P, ws + OFF_G);
    k_ntn<<<8 * 16, 256, 0, stream>>>(ws + OFF_G, V_ntn, W_ntn, b_ntn, ws + OFF_S);
    k_out<<<8, 64, 0, stream>>>(ws + OFF_S, p0, p1, p2, p3, out);
}